// Round 8
// baseline (205.999 us; speedup 1.0000x reference)
//
#include <hip/hip_runtime.h>
#include <hip/hip_bf16.h>

// RelativeAttention: B=2,H=16,L=2048,D=64, fp32 in/out.
// R10: 2-deep cross-tile pipeline (T15). R9 proved spill-free + 4 waves/EU
//     changes nothing (R4 2w=68.5us, R9 4w=72.8us) -> not latency-bound;
//     the barrier-lockstep phase bursts (LDS->QK->softmax->PV) leave every
//     pipe idle between bursts. Fix: overlap ACROSS tiles within each wave:
//       iter kt: QK(kt) MFMA  (indep of) softmax(kt-1) VALU   [merge bursts]
//                stage(kt+1) cvt-VALU  (indep of) PV(kt-1) MFMA
//                loadKV(kt+2)  -> full-iteration vmcnt window (fixes R9's
//                                 short QK-only window regression)
//     Two sacc states, STATIC names sA/sB (rule #20), AGPR = 32 oacc + 2x16
//     sacc = 64 exact. K double-buffered; V TRIPLE-buffered (PV reads slot
//     (kt-1)%3 while staging writes (kt+1)%3; all pairs barrier-separated).
//     setprio dropped: would fence the scheduler against exactly this merge.
//     Keeps: LDS pad pins 2 blocks/CU, k-split wave pairs, no-max softmax,
//     1 barrier/iter, dword-packed V^T staging. WRITE_SIZE=16384 is the
//     no-spill canary.

#define LOG2E 1.44269504088896f

constexpr int Lv = 2048, Dv = 64;
constexpr int BH  = 32;        // B*H
constexpr int BQ  = 128;       // q rows per block (4 pairs x 32)
constexpr int BKT = 64;        // k-tile
constexpr int NQT = Lv / BQ;   // 16
constexpr int NKT = Lv / BKT;  // 32
constexpr int LDK = 72;        // LDS row stride (bf16), +8 pad
constexpr int LDO = 68;        // epilogue combine row stride (f32), +4 pad
constexpr int MAXREL = 8;

typedef __bf16 bf16x8 __attribute__((ext_vector_type(8)));
typedef __bf16 bf16x4 __attribute__((ext_vector_type(4)));
typedef float  f32x4  __attribute__((ext_vector_type(4)));

static __device__ __forceinline__ unsigned pack2bf(float a, float b) {
    __bf16 x = (__bf16)a, y = (__bf16)b;
    unsigned short ux = __builtin_bit_cast(unsigned short, x);
    unsigned short uy = __builtin_bit_cast(unsigned short, y);
    return (unsigned)ux | ((unsigned)uy << 16);
}

__global__
__attribute__((amdgpu_flat_work_group_size(512, 512), amdgpu_waves_per_eu(4, 4)))
void relattn_kernel(
    const float* __restrict__ Q, const float* __restrict__ K,
    const float* __restrict__ V, const float* __restrict__ RB,
    float* __restrict__ O)
{
    constexpr int KBYTES   = 2 * BKT * LDK * 2;   // 18432 (K double)
    constexpr int VBYTES   = 3 * Dv  * LDK * 2;   // 27648 (V triple)
    constexpr int PADBYTES = 10240;  // pin: 56320 B > 160KiB/3 -> 2 blocks/CU
    __shared__ __align__(16) unsigned char smem[KBYTES + VBYTES + PADBYTES];
    __shared__ float sRB[2 * MAXREL + 1];
    __bf16* sK = (__bf16*)smem;                  // [2][BKT*LDK]  K-tile [kk][d]
    __bf16* sV = (__bf16*)(smem + KBYTES);       // [3][Dv*LDK]   V^T [d][perm(kk)]

    const int tid  = threadIdx.x;
    const int w    = tid >> 6;     // wave 0..7
    const int lane = tid & 63;
    const int l16  = lane & 15;
    const int lg   = lane >> 4;    // 0..3
    const int pair = w >> 1;       // 0..3: which 32-q sub-tile
    const int wh   = w & 1;        // 0/1:  which kk half of every k-tile

    const int bh = blockIdx.x & (BH - 1);  // same-bh blocks share XCD (bid%8)
    const int qt = blockIdx.x >> 5;

    const size_t base = (size_t)bh * Lv * Dv;
    const float* Qb = Q + base + (size_t)qt * BQ * Dv;
    const float* Kb = K + base;
    const float* Vb = V + base;
    float*       Ob = O + base + (size_t)qt * BQ * Dv;

    if (tid < 2 * MAXREL + 1) sRB[tid] = RB[tid] * LOG2E;  // log2-domain bias

    // ---- Q B-fragments from global, scale folded in ----
    const float qsc = 0.125f * LOG2E;
    bf16x8 qfrag[2][2];   // [h][s]: n = l16, k = lg*8 + j + 32*s
    #pragma unroll
    for (int h = 0; h < 2; ++h) {
        const float* qrow = Qb + (pair * 32 + h * 16 + l16) * Dv;
        #pragma unroll
        for (int s = 0; s < 2; ++s) {
            const float4 a = *(const float4*)(qrow + lg * 8 + 32 * s);
            const float4 b = *(const float4*)(qrow + lg * 8 + 32 * s + 4);
            bf16x8 f;
            f[0] = (__bf16)(a.x * qsc); f[1] = (__bf16)(a.y * qsc);
            f[2] = (__bf16)(a.z * qsc); f[3] = (__bf16)(a.w * qsc);
            f[4] = (__bf16)(b.x * qsc); f[5] = (__bf16)(b.y * qsc);
            f[6] = (__bf16)(b.z * qsc); f[7] = (__bf16)(b.w * qsc);
            qfrag[h][s] = f;
        }
    }

    f32x4 oacc[2][4];     // [h][t]: partial O[q=l16][d = t*16 + lg*4 + r] (kk half)
    float lacc[2][2];     // per-lane partial row sums (kk half), 2 chains per h
    #pragma unroll
    for (int h = 0; h < 2; ++h) {
        lacc[h][0] = 0.f; lacc[h][1] = 0.f;
        #pragma unroll
        for (int t = 0; t < 4; ++t)
            #pragma unroll
            for (int r = 0; r < 4; ++r) oacc[h][t][r] = 0.f;
    }

    // ---- staging indices (512 threads stage the full tile) ----
    const int kr0 = tid >> 4;              // K: row base (p*32 + kr0), 0..31
    const int kc4 = (tid & 15) * 4;        // K: col (float4)
    const int vkk0 = (tid & 31) * 2;       // V: kk pair (vkk0, vkk0+1)
    const int vd0  = (tid >> 5) * 4;       // V: d range [vd0, vd0+4)
    // kk -> mfma-k bit permutation: [t1,t0,lg1,lg0,r1,r0] -> [t1,lg1,lg0,t0,r1,r0]
    const int vcol = (vkk0 & 35) | ((vkk0 & 12) << 1) | ((vkk0 & 16) >> 2); // even

    float4 kreg[2], vreg[2];   // loaded at iter kt, staged at iter kt+1

    auto loadKV = [&](int kt) {
        const float* Ks = Kb + (size_t)kt * BKT * Dv;
        const float* Vs = Vb + (size_t)kt * BKT * Dv;
        kreg[0] = *(const float4*)(Ks + kr0 * Dv + kc4);
        kreg[1] = *(const float4*)(Ks + (32 + kr0) * Dv + kc4);
        vreg[0] = *(const float4*)(Vs + vkk0 * Dv + vd0);
        vreg[1] = *(const float4*)(Vs + (vkk0 + 1) * Dv + vd0);
    };
    auto stageKV = [&](int kb, int vslot) {  // convert + write; state transient
        __bf16* sKb = sK + kb * (BKT * LDK);
        __bf16* sVb = sV + vslot * (Dv * LDK);
        #pragma unroll
        for (int p = 0; p < 2; ++p) {
            bf16x4 pk;
            pk[0] = (__bf16)kreg[p].x; pk[1] = (__bf16)kreg[p].y;
            pk[2] = (__bf16)kreg[p].z; pk[3] = (__bf16)kreg[p].w;
            *(bf16x4*)&sKb[(p * 32 + kr0) * LDK + kc4] = pk;
        }
        #pragma unroll
        for (int j = 0; j < 4; ++j)
            *(unsigned*)&sVb[(vd0 + j) * LDK + vcol] =
                pack2bf(vreg[0][j], vreg[1][j]);
    };

    const int qw0 = qt * BQ + pair * 32;   // pair's first q row
    const int qgl = qw0 + l16;             // lane's q row (h=0; +16 for h=1)

    // softmax of tile (prev sacc) -> pfrag + lacc
    auto softmax = [&](int ktp, f32x4 (&sacc)[2][2], bf16x8 (&pfrag)[2]) {
        const int k0 = ktp * BKT + wh * 32;
        #pragma unroll
        for (int h = 0; h < 2; ++h) {
            const int qlo = qw0 + h * 16;
            if (k0 >= qlo + 15 + MAXREL) {               // right of band
                const float bc = sRB[2 * MAXREL];
                #pragma unroll
                for (int tl = 0; tl < 2; ++tl)
                    #pragma unroll
                    for (int r = 0; r < 4; ++r) {
                        float p = __builtin_amdgcn_exp2f(sacc[h][tl][r] + bc);
                        lacc[h][r & 1] += p;
                        pfrag[h][tl * 4 + r] = (__bf16)p;
                    }
            } else if (k0 + 31 + MAXREL <= qlo) {        // left of band
                const float bc = sRB[0];
                #pragma unroll
                for (int tl = 0; tl < 2; ++tl)
                    #pragma unroll
                    for (int r = 0; r < 4; ++r) {
                        float p = __builtin_amdgcn_exp2f(sacc[h][tl][r] + bc);
                        lacc[h][r & 1] += p;
                        pfrag[h][tl * 4 + r] = (__bf16)p;
                    }
            } else {                                     // diagonal band
                const int kkb = k0 + lg * 4 - (qgl + h * 16);
                #pragma unroll
                for (int tl = 0; tl < 2; ++tl) {
                    #pragma unroll
                    for (int r = 0; r < 4; ++r) {
                        int d = kkb + tl * 16 + r;
                        d = d < -MAXREL ? -MAXREL : (d > MAXREL ? MAXREL : d);
                        float p = __builtin_amdgcn_exp2f(sacc[h][tl][r] + sRB[d + MAXREL]);
                        lacc[h][r & 1] += p;
                        pfrag[h][tl * 4 + r] = (__bf16)p;
                    }
                }
            }
        }
    };

    auto qk = [&](int kt, f32x4 (&cur)[2][2]) {
        __bf16* sKb = sK + (kt & 1) * (BKT * LDK);
        #pragma unroll
        for (int h = 0; h < 2; ++h)
            #pragma unroll
            for (int tl = 0; tl < 2; ++tl)
                #pragma unroll
                for (int r = 0; r < 4; ++r) cur[h][tl][r] = 0.f;
        #pragma unroll
        for (int s = 0; s < 2; ++s) {
            #pragma unroll
            for (int tl = 0; tl < 2; ++tl) {
                bf16x8 a = *(const bf16x8*)&sKb[((2 * wh + tl) * 16 + l16) * LDK + lg * 8 + 32 * s];
                cur[0][tl] = __builtin_amdgcn_mfma_f32_16x16x32_bf16(a, qfrag[0][s], cur[0][tl], 0, 0, 0);
                cur[1][tl] = __builtin_amdgcn_mfma_f32_16x16x32_bf16(a, qfrag[1][s], cur[1][tl], 0, 0, 0);
            }
        }
    };

    auto pv = [&](int vslot, bf16x8 (&pfrag)[2]) {
        __bf16* sVr = sV + vslot * (Dv * LDK);
        #pragma unroll
        for (int t = 0; t < 4; ++t) {
            bf16x8 vf = *(const bf16x8*)&sVr[(t * 16 + l16) * LDK + lg * 8 + 32 * wh];
            oacc[0][t] = __builtin_amdgcn_mfma_f32_16x16x32_bf16(vf, pfrag[0], oacc[0][t], 0, 0, 0);
            oacc[1][t] = __builtin_amdgcn_mfma_f32_16x16x32_bf16(vf, pfrag[1], oacc[1][t], 0, 0, 0);
        }
    };

    f32x4 sA[2][2], sB[2][2];   // two in-flight score states (static names)

    // ---- prologue ----
    loadKV(0);
    stageKV(0, 0);            // tile 0 -> kbuf0, vslot0
    loadKV(1);
    __syncthreads();
    qk(0, sA);                // QK(0); softmax deferred into iter 1
    stageKV(1, 1);            // tile 1 -> kbuf1, vslot1
    loadKV(2);
    __syncthreads();

    // ---- main pipeline: iter kt does QK(kt) || softmax(kt-1), then
    //      stage(kt+1) || PV(kt-1). One barrier per iter. ----
    auto ITER = [&](int kt, f32x4 (&cur)[2][2], f32x4 (&prev)[2][2],
                    int rs, int ws) {
        qk(kt, cur);                           // MFMA burst (tile kt)
        bf16x8 pfrag[2];
        softmax(kt - 1, prev, pfrag);          // VALU burst (tile kt-1) - indep
        if (kt + 1 < NKT) stageKV((kt + 1) & 1, ws);  // cvt VALU + ds_write
        if (kt + 2 < NKT) loadKV(kt + 2);      // full-iteration vmcnt window
        pv(rs, pfrag);                         // MFMA burst (tile kt-1) - indep
        __syncthreads();
    };

    int rs = 0, ws = 2;   // PV reads (kt-1)%3, stage writes (kt+1)%3; kt=1
    for (int k2 = 1; k2 < NKT - 1; k2 += 2) {
        ITER(k2,     sB, sA, rs, ws);
        rs = (rs == 2) ? 0 : rs + 1; ws = (ws == 2) ? 0 : ws + 1;
        ITER(k2 + 1, sA, sB, rs, ws);
        rs = (rs == 2) ? 0 : rs + 1; ws = (ws == 2) ? 0 : ws + 1;
    }
    ITER(NKT - 1, sB, sA, rs, ws);             // kt=31: stage/load guarded off

    // ---- epilogue: finish tile 31 (softmax + PV from vslot 31%3 = 1) ----
    {
        bf16x8 pfrag[2];
        softmax(NKT - 1, sB, pfrag);
        pv((NKT - 1) % 3, pfrag);
    }

    // ---- epilogue: combine wave-pair partials via LDS, normalize, store ----
    float lh[2];
    #pragma unroll
    for (int h = 0; h < 2; ++h) {
        float l = lacc[h][0] + lacc[h][1];
        l += __shfl_xor(l, 16);
        l += __shfl_xor(l, 32);
        lh[h] = l;
    }

    __syncthreads();   // all tile reads done before smem is repurposed
    float* sO = (float*)smem;                          // [4][32][LDO]
    float* sL = (float*)(smem + 4 * 32 * LDO * 4);     // [4][32]
    if (wh == 1) {
        #pragma unroll
        for (int h = 0; h < 2; ++h) {
            #pragma unroll
            for (int t = 0; t < 4; ++t)
                *(f32x4*)&sO[(pair * 32 + h * 16 + l16) * LDO + t * 16 + lg * 4] = oacc[h][t];
            if (lg == 0) sL[pair * 32 + h * 16 + l16] = lh[h];
        }
    }
    __syncthreads();
    if (wh == 0) {
        #pragma unroll
        for (int h = 0; h < 2; ++h) {
            const float lt = lh[h] + sL[pair * 32 + h * 16 + l16];
            const float linv = 1.f / lt;
            float* orow = Ob + (pair * 32 + h * 16 + l16) * Dv;
            #pragma unroll
            for (int t = 0; t < 4; ++t) {
                f32x4 oo = *(const f32x4*)&sO[(pair * 32 + h * 16 + l16) * LDO + t * 16 + lg * 4];
                float4 o;
                o.x = (oacc[h][t][0] + oo[0]) * linv;
                o.y = (oacc[h][t][1] + oo[1]) * linv;
                o.z = (oacc[h][t][2] + oo[2]) * linv;
                o.w = (oacc[h][t][3] + oo[3]) * linv;
                *(float4*)(orow + t * 16 + lg * 4) = o;
            }
        }
    }
}

extern "C" void kernel_launch(void* const* d_in, const int* in_sizes, int n_in,
                              void* d_out, int out_size, void* d_ws, size_t ws_size,
                              hipStream_t stream) {
    const float* q  = (const float*)d_in[0];
    const float* k  = (const float*)d_in[1];
    const float* v  = (const float*)d_in[2];
    const float* rb = (const float*)d_in[3];
    float* out = (float*)d_out;
    relattn_kernel<<<dim3(BH * NQT), dim3(512), 0, stream>>>(q, k, v, rb, out);
}

// Round 10
// 136.947 us; speedup vs baseline: 1.5042x; 1.5042x over previous
//
#include <hip/hip_runtime.h>
#include <hip/hip_bf16.h>

// RelativeAttention: B=2,H=16,L=2048,D=64, fp32 in/out.
// R11 (resubmit; R9 bench was a GPUAcquisitionTimeout, no data):
//     R8 structure (best measured: 67-70us) + VALU->MFMA offload.
//     R10's 2-deep pipeline spilled 60 dwords/thread (WRITE 78MB, 135us):
//     T15 doesn't fit the 64-reg arch partition -- reverted. R9/R4 showed
//     occupancy/TLP isn't binding; VALU (44%) is the largest pipe. Cut it:
//     (1) bias-add -> QK MFMA C-init: init sacc with log2-domain bias
//         (uniform tiles: 16 movs replace 16 movs + 16 adds).
//     (2) rowsum -> ones-MFMA: lfrag = mfma(ones, pfrag, lfrag) puts P
//         rowsums on the 19%-busy matrix pipe; kills 16 VALU adds/thread/
//         iter, the lacc chains, and the epilogue shuffles (each acc reg
//         holds the full q-rowsum; norm now consistent with bf16 P).
//     Net -32 VALU instr/thread/iter (~25% of VALU), AGPR 48->56 (free),
//     arch regs -2 (may clear R8's 4MB spill residue).
//     Keeps R8: k-split wave pairs, stage-from-held-packed-regs at top of
//     iter, loads pre-barrier, convert after QK, no-max softmax, double-
//     buffered LDS, 1 barrier/iter, LDS pad pins 2 blocks/CU, no setprio.

#define LOG2E 1.44269504088896f

constexpr int Lv = 2048, Dv = 64;
constexpr int BH  = 32;        // B*H
constexpr int BQ  = 128;       // q rows per block (4 pairs x 32)
constexpr int BKT = 64;        // k-tile
constexpr int NQT = Lv / BQ;   // 16
constexpr int NKT = Lv / BKT;  // 32
constexpr int LDK = 72;        // LDS row stride (bf16), +8 pad
constexpr int LDO = 68;        // epilogue combine row stride (f32), +4 pad
constexpr int MAXREL = 8;

typedef __bf16 bf16x8 __attribute__((ext_vector_type(8)));
typedef __bf16 bf16x4 __attribute__((ext_vector_type(4)));
typedef float  f32x4  __attribute__((ext_vector_type(4)));

static __device__ __forceinline__ unsigned pack2bf(float a, float b) {
    __bf16 x = (__bf16)a, y = (__bf16)b;
    unsigned short ux = __builtin_bit_cast(unsigned short, x);
    unsigned short uy = __builtin_bit_cast(unsigned short, y);
    return (unsigned)ux | ((unsigned)uy << 16);
}

__global__
__attribute__((amdgpu_flat_work_group_size(512, 512), amdgpu_waves_per_eu(4, 4)))
void relattn_kernel(
    const float* __restrict__ Q, const float* __restrict__ K,
    const float* __restrict__ V, const float* __restrict__ RB,
    float* __restrict__ O)
{
    constexpr int SKBYTES  = 2 * BKT * LDK * 2;   // 18432
    constexpr int SVBYTES  = 2 * Dv  * LDK * 2;   // 18432
    constexpr int PADBYTES = 20480;  // occupancy pin: total LDS 57.4KB > 160KiB/3
                                     // -> HW caps at 2 blocks/CU = 4 waves/EU.
    __shared__ __align__(16) unsigned char smem[SKBYTES + SVBYTES + PADBYTES];
    __shared__ float sRB[2 * MAXREL + 1];
    __bf16* sK = (__bf16*)smem;                  // [2][BKT*LDK]  K-tile [kk][d]
    __bf16* sV = (__bf16*)(smem + SKBYTES);      // [2][Dv*LDK]   V^T [d][perm(kk)]

    const int tid  = threadIdx.x;
    const int w    = tid >> 6;     // wave 0..7
    const int lane = tid & 63;
    const int l16  = lane & 15;
    const int lg   = lane >> 4;    // 0..3
    const int pair = w >> 1;       // 0..3: which 32-q sub-tile
    const int wh   = w & 1;        // 0/1:  which kk half of every k-tile

    const int bh = blockIdx.x & (BH - 1);  // same-bh blocks share XCD (bid%8)
    const int qt = blockIdx.x >> 5;

    const size_t base = (size_t)bh * Lv * Dv;
    const float* Qb = Q + base + (size_t)qt * BQ * Dv;
    const float* Kb = K + base;
    const float* Vb = V + base;
    float*       Ob = O + base + (size_t)qt * BQ * Dv;

    if (tid < 2 * MAXREL + 1) sRB[tid] = RB[tid] * LOG2E;  // log2-domain bias

    // ---- Q B-fragments from global, scale folded in ----
    const float qsc = 0.125f * LOG2E;
    bf16x8 qfrag[2][2];   // [h][s]: n = l16, k = lg*8 + j + 32*s
    #pragma unroll
    for (int h = 0; h < 2; ++h) {
        const float* qrow = Qb + (pair * 32 + h * 16 + l16) * Dv;
        #pragma unroll
        for (int s = 0; s < 2; ++s) {
            const float4 a = *(const float4*)(qrow + lg * 8 + 32 * s);
            const float4 b = *(const float4*)(qrow + lg * 8 + 32 * s + 4);
            bf16x8 f;
            f[0] = (__bf16)(a.x * qsc); f[1] = (__bf16)(a.y * qsc);
            f[2] = (__bf16)(a.z * qsc); f[3] = (__bf16)(a.w * qsc);
            f[4] = (__bf16)(b.x * qsc); f[5] = (__bf16)(b.y * qsc);
            f[6] = (__bf16)(b.z * qsc); f[7] = (__bf16)(b.w * qsc);
            qfrag[h][s] = f;
        }
    }

    // ---- ones A-fragment for the rowsum MFMA ----
    bf16x8 ones;
    #pragma unroll
    for (int j = 0; j < 8; ++j) ones[j] = (__bf16)1.0f;

    f32x4 oacc[2][4];     // [h][t]: partial O[q=l16][d = t*16 + lg*4 + r] (kk half)
    f32x4 lfrag[2];       // [h]: rowsum accumulator via ones-MFMA (all regs equal)
    #pragma unroll
    for (int h = 0; h < 2; ++h) {
        #pragma unroll
        for (int r = 0; r < 4; ++r) lfrag[h][r] = 0.f;
        #pragma unroll
        for (int t = 0; t < 4; ++t)
            #pragma unroll
            for (int r = 0; r < 4; ++r) oacc[h][t][r] = 0.f;
    }

    // ---- staging indices (512 threads stage the full tile) ----
    const int kr0 = tid >> 4;              // K: row base (p*32 + kr0), 0..31
    const int kc4 = (tid & 15) * 4;        // K: col (float4)
    const int vkk0 = (tid & 31) * 2;       // V: kk pair (vkk0, vkk0+1)
    const int vd0  = (tid >> 5) * 4;       // V: d range [vd0, vd0+4)
    // kk -> mfma-k bit permutation: [t1,t0,lg1,lg0,r1,r0] -> [t1,lg1,lg0,t0,r1,r0]
    const int vcol = (vkk0 & 35) | ((vkk0 & 12) << 1) | ((vkk0 & 16) >> 2); // even

    float4 kreg[2], vreg[2];   // load destinations (transient: issue -> convert)
    bf16x4   kpk[2];           // packed K rows  (live across barrier)
    unsigned vpk[4];           // packed V dwords (live across barrier)

    auto loadKV = [&](int kt) {
        const float* Ks = Kb + (size_t)kt * BKT * Dv;
        const float* Vs = Vb + (size_t)kt * BKT * Dv;
        kreg[0] = *(const float4*)(Ks + kr0 * Dv + kc4);
        kreg[1] = *(const float4*)(Ks + (32 + kr0) * Dv + kc4);
        vreg[0] = *(const float4*)(Vs + vkk0 * Dv + vd0);
        vreg[1] = *(const float4*)(Vs + (vkk0 + 1) * Dv + vd0);
    };
    auto convKV = [&]() {   // f32 -> packed bf16; frees the 16 f32 load regs
        #pragma unroll
        for (int p = 0; p < 2; ++p) {
            bf16x4 pk;
            pk[0] = (__bf16)kreg[p].x; pk[1] = (__bf16)kreg[p].y;
            pk[2] = (__bf16)kreg[p].z; pk[3] = (__bf16)kreg[p].w;
            kpk[p] = pk;
        }
        #pragma unroll
        for (int j = 0; j < 4; ++j)
            vpk[j] = pack2bf(vreg[0][j], vreg[1][j]);
    };

    loadKV(0);
    convKV();

    const int qw0 = qt * BQ + pair * 32;   // pair's first q row
    const int qgl = qw0 + l16;             // lane's q row (h=0; +16 for h=1)

    for (int kt = 0; kt < NKT; ++kt) {
        const int buf = kt & 1;
        __bf16* sKb = sK + buf * (BKT * LDK);
        __bf16* sVb = sV + buf * (Dv * LDK);

        // ---- stage packed regs -> LDS[buf] ----
        *(bf16x4*)&sKb[kr0 * LDK + kc4]          = kpk[0];
        *(bf16x4*)&sKb[(32 + kr0) * LDK + kc4]   = kpk[1];
        #pragma unroll
        for (int j = 0; j < 4; ++j)
            *(unsigned*)&sVb[(vd0 + j) * LDK + vcol] = vpk[j];
        if (kt + 1 < NKT) loadKV(kt + 1);   // issue next global loads pre-barrier
        __syncthreads();   // single barrier per iter (double-buffered)

        // ---- sacc init = log2-domain bias (folds the bias add into MFMA C) ----
        const int k0 = kt * BKT + wh * 32;   // wave's kk base
        f32x4 sacc[2][2];   // [h][tl]
        #pragma unroll
        for (int h = 0; h < 2; ++h) {
            const int qlo = qw0 + h * 16;
            if (k0 >= qlo + 15 + MAXREL) {               // half-tile right of band
                const float bc = sRB[2 * MAXREL];
                #pragma unroll
                for (int tl = 0; tl < 2; ++tl)
                    #pragma unroll
                    for (int r = 0; r < 4; ++r) sacc[h][tl][r] = bc;
            } else if (k0 + 31 + MAXREL <= qlo) {        // half-tile left of band
                const float bc = sRB[0];
                #pragma unroll
                for (int tl = 0; tl < 2; ++tl)
                    #pragma unroll
                    for (int r = 0; r < 4; ++r) sacc[h][tl][r] = bc;
            } else {                                     // diagonal band half-tile
                const int kkb = k0 + lg * 4 - (qgl + h * 16);
                #pragma unroll
                for (int tl = 0; tl < 2; ++tl) {
                    #pragma unroll
                    for (int r = 0; r < 4; ++r) {
                        int d = kkb + tl * 16 + r;
                        d = d < -MAXREL ? -MAXREL : (d > MAXREL ? MAXREL : d);
                        sacc[h][tl][r] = sRB[d + MAXREL];
                    }
                }
            }
        }

        // ---- S^T = K Q^T + bias on this wave's kk half (t_g = 2*wh + tl) ----
        #pragma unroll
        for (int s = 0; s < 2; ++s) {
            #pragma unroll
            for (int tl = 0; tl < 2; ++tl) {
                bf16x8 a = *(const bf16x8*)&sKb[((2 * wh + tl) * 16 + l16) * LDK + lg * 8 + 32 * s];
                sacc[0][tl] = __builtin_amdgcn_mfma_f32_16x16x32_bf16(a, qfrag[0][s], sacc[0][tl], 0, 0, 0);
                sacc[1][tl] = __builtin_amdgcn_mfma_f32_16x16x32_bf16(a, qfrag[1][s], sacc[1][tl], 0, 0, 0);
            }
        }

        // ---- convert in-flight loads now: QK phase covered the HBM latency ----
        if (kt + 1 < NKT) convKV();

        // ---- softmax: pure exp2 + pack (no bias add, no rowsum adds) ----
        bf16x8 pfrag[2];                     // [h]: j = tl*4 + r, used at s=wh
        #pragma unroll
        for (int h = 0; h < 2; ++h)
            #pragma unroll
            for (int tl = 0; tl < 2; ++tl)
                #pragma unroll
                for (int r = 0; r < 4; ++r)
                    pfrag[h][tl * 4 + r] =
                        (__bf16)__builtin_amdgcn_exp2f(sacc[h][tl][r]);

        // ---- rowsum on the matrix pipe: lfrag += ones * P^T ----
        lfrag[0] = __builtin_amdgcn_mfma_f32_16x16x32_bf16(ones, pfrag[0], lfrag[0], 0, 0, 0);
        lfrag[1] = __builtin_amdgcn_mfma_f32_16x16x32_bf16(ones, pfrag[1], lfrag[1], 0, 0, 0);

        // ---- O^T += V^T(kk half) P^T : one MFMA per (h,t), s = wh ----
        #pragma unroll
        for (int t = 0; t < 4; ++t) {
            bf16x8 vf = *(const bf16x8*)&sVb[(t * 16 + l16) * LDK + lg * 8 + 32 * wh];
            oacc[0][t] = __builtin_amdgcn_mfma_f32_16x16x32_bf16(vf, pfrag[0], oacc[0][t], 0, 0, 0);
            oacc[1][t] = __builtin_amdgcn_mfma_f32_16x16x32_bf16(vf, pfrag[1], oacc[1][t], 0, 0, 0);
        }
    }

    // ---- epilogue: combine wave-pair partials via LDS, normalize, store ----
    // lfrag[h]: every reg of every lane holds rowsum(q=l16) -- no shuffles.
    float lh[2];
    lh[0] = lfrag[0][0];
    lh[1] = lfrag[1][0];

    __syncthreads();   // all tile reads done before smem is repurposed
    float* sO = (float*)smem;                          // [4][32][LDO]
    float* sL = (float*)(smem + 4 * 32 * LDO * 4);     // [4][32]
    if (wh == 1) {
        #pragma unroll
        for (int h = 0; h < 2; ++h) {
            #pragma unroll
            for (int t = 0; t < 4; ++t)
                *(f32x4*)&sO[(pair * 32 + h * 16 + l16) * LDO + t * 16 + lg * 4] = oacc[h][t];
            if (lg == 0) sL[pair * 32 + h * 16 + l16] = lh[h];
        }
    }
    __syncthreads();
    if (wh == 0) {
        #pragma unroll
        for (int h = 0; h < 2; ++h) {
            const float lt = lh[h] + sL[pair * 32 + h * 16 + l16];
            const float linv = 1.f / lt;
            float* orow = Ob + (pair * 32 + h * 16 + l16) * Dv;
            #pragma unroll
            for (int t = 0; t < 4; ++t) {
                f32x4 oo = *(const f32x4*)&sO[(pair * 32 + h * 16 + l16) * LDO + t * 16 + lg * 4];
                float4 o;
                o.x = (oacc[h][t][0] + oo[0]) * linv;
                o.y = (oacc[h][t][1] + oo[1]) * linv;
                o.z = (oacc[h][t][2] + oo[2]) * linv;
                o.w = (oacc[h][t][3] + oo[3]) * linv;
                *(float4*)(orow + t * 16 + lg * 4) = o;
            }
        }
    }
}

extern "C" void kernel_launch(void* const* d_in, const int* in_sizes, int n_in,
                              void* d_out, int out_size, void* d_ws, size_t ws_size,
                              hipStream_t stream) {
    const float* q  = (const float*)d_in[0];
    const float* k  = (const float*)d_in[1];
    const float* v  = (const float*)d_in[2];
    const float* rb = (const float*)d_in[3];
    float* out = (float*)d_out;
    relattn_kernel<<<dim3(BH * NQT), dim3(512), 0, stream>>>(q, k, v, rb, out);
}